// Round 7
// baseline (57.586 us; speedup 1.0000x reference)
//
#include <hip/hip_runtime.h>

typedef __attribute__((ext_vector_type(8))) short bf16x8_t;   // 8 bf16 (4 VGPRs)
typedef __attribute__((ext_vector_type(4))) float f32x4_t;    // MFMA accumulator

#define SLOTS 48   // max supported in-slot degree; overflow falls back to atomics

__device__ __forceinline__ unsigned short f2bf(float f) {
    union { float f; unsigned int i; } v; v.f = f;
    unsigned int u = v.i;
    return (unsigned short)((u + 0x7FFFu + ((u >> 16) & 1u)) >> 16);   // RNE
}

__device__ __forceinline__ unsigned int cvt_pk_bf16(float lo, float hi) {
    unsigned int r;
    asm("v_cvt_pk_bf16_f32 %0, %1, %2" : "=v"(r) : "v"(lo), "v"(hi));
    return r;
}

// d_ws layout:
//   [0      ..  19456)  u16 tab: W1p frags (2 KB) + W2p frags (17 KB)
//   [65536  .. 265536)  int cnt[n_nodes]
//   [524288 .. +128e6)  float msgslot[n_nodes][SLOTS][16]

// ============ kernel 1: fused {root-init + cnt-zero | fragment-table prep} ============
__global__ __launch_bounds__(256) void prep_kernel(
    const float* __restrict__ x,       // [N,16]
    const float* __restrict__ W1,      // [8,32]
    const float* __restrict__ b1,      // [32]
    const float* __restrict__ W2,      // [32,256]
    const float* __restrict__ b2,      // [256]
    const float* __restrict__ rootk,   // [16,16]
    const float* __restrict__ bias,    // [16]
    float* __restrict__ out,           // [N,16]
    unsigned short* __restrict__ tab,
    int* __restrict__ cnt,             // may be null (no-slots mode)
    int n_nodes, int root_blocks)
{
    const int tid = threadIdx.x;
    const int bid = blockIdx.x;

    if (bid < root_blocks) {
        __shared__ float sR[256];
        __shared__ float sB[16];
        if (tid < 256) sR[tid] = rootk[tid];
        if (tid < 16)  sB[tid] = bias[tid];
        __syncthreads();

        int nid = bid * 256 + tid;
        if (nid >= n_nodes) return;
        if (cnt) cnt[nid] = 0;

        const float* xp = x + (size_t)nid * 16;
        float xf[16];
#pragma unroll
        for (int f = 0; f < 16; f += 4) {
            float4 v = *reinterpret_cast<const float4*>(xp + f);
            xf[f] = v.x; xf[f + 1] = v.y; xf[f + 2] = v.z; xf[f + 3] = v.w;
        }
        float o[16];
#pragma unroll
        for (int cc = 0; cc < 16; ++cc) o[cc] = sB[cc];
#pragma unroll
        for (int f = 0; f < 16; ++f) {
            float p = xf[f];
#pragma unroll
            for (int cc = 0; cc < 16; ++cc)
                o[cc] = fmaf(p, sR[f * 16 + cc], o[cc]);
        }
        float* dst = out + (size_t)nid * 16;
#pragma unroll
        for (int cc = 0; cc < 16; cc += 4)
            *reinterpret_cast<float4*>(dst + cc) = make_float4(o[cc], o[cc+1], o[cc+2], o[cc+3]);
    } else {
        // ---- fragment tables: 19 groups of 64 lanes ----
        for (int it = tid; it < 64 * 19; it += 256) {
            int grp  = it >> 6;         // 0,1 -> W1p halves; 2..18 -> W2p steps
            int lane = it & 63;
            int q = lane >> 4, cc = lane & 15;
            union { unsigned short h[8]; uint4 u; } pk;
            if (grp < 2) {
                int hh = grp;
#pragma unroll
                for (int j = 0; j < 8; ++j) {
                    float v = 0.f;
                    if (q == 0)              v = W1[j * 32 + cc + 16 * hh];
                    else if (q == 1 && j==0) v = b1[cc + 16 * hh];
                    pk.h[j] = f2bf(v);
                }
                *reinterpret_cast<uint4*>(tab + ((size_t)hh * 64 + lane) * 8) = pk.u;
            } else {
                int s = grp - 2;        // K-step
#pragma unroll
                for (int j = 0; j < 8; ++j) {
                    float v;
                    if (s < 16) {
                        int hd = (j < 4) ? (4 * q + j) : (4 * q + 12 + j);  // perm
                        v = W2[hd * 256 + s * 16 + cc];
                    } else {
                        v = (q < 2) ? b2[(q * 8 + j) * 16 + cc] : 0.f;       // b2 fold
                    }
                    pk.h[j] = f2bf(v);
                }
                *reinterpret_cast<uint4*>(tab + 1024 + ((size_t)s * 64 + lane) * 8) = pk.u;
            }
        }
    }
}

// ============ kernel 2: MFMA edge kernel ============
// USE_SLOTS=1: slot-scatter (1 int atomic/edge + coalesced 64B line store)
// USE_SLOTS=0: direct f32 atomics (fallback when ws too small)
template<int USE_SLOTS>
__global__ __launch_bounds__(256) void edge_mfma_kernel(
    const float* __restrict__ x,       // [N,16]
    const float* __restrict__ efeat,   // [E,8]
    const int*   __restrict__ idx_i,
    const int*   __restrict__ idx_j,
    const unsigned short* __restrict__ tab,
    float* __restrict__ out,           // [N,16], pre-initialized with root term
    float* __restrict__ msgslot,       // [N][SLOTS][16]
    int*   __restrict__ cnt,           // [N]
    int n_edges, int n_groups)
{
    const int lane = threadIdx.x & 63;
    const int q = lane >> 4;
    const int c = lane & 15;

    // ---- per-wave fragment preload ----
    const bf16x8_t* w1f = reinterpret_cast<const bf16x8_t*>(tab) + lane;
    const bf16x8_t aW1_0 = w1f[0];
    const bf16x8_t aW1_1 = w1f[64];
    const bf16x8_t* w2f = reinterpret_cast<const bf16x8_t*>(tab + 1024) + lane;
    bf16x8_t bW2[17];
#pragma unroll
    for (int s = 0; s < 17; ++s) bW2[s] = w2f[s * 64];

    const unsigned int c1 = (q == 1) ? 0x00003F80u : 0u;   // bf16(1.0) one-hot for b1 row
    const bool isq0 = (q == 0);
    const bool qodd = (q & 1);

    int g = blockIdx.x * 4 + (threadIdx.x >> 6);
    const int nw = gridDim.x * 4;
    if (g >= n_groups) return;

    // prologue: first group's source index
    int  eid = g * 16 + c;
    bool va  = (eid < n_edges);
    int  el  = va ? eid : (n_edges - 1);
    int  jsrc = idx_j[el];

    for (; g < n_groups; g += nw) {
        const int base = g * 16;

        // ---- scatter targets for rows q*4..q*4+3 (same for all 16 lanes of group q) ----
        int t0, t1, t2, t3;
        if (base + 16 <= n_edges) {
            int4 tv = *reinterpret_cast<const int4*>(idx_i + base + q * 4);
            t0 = tv.x; t1 = tv.y; t2 = tv.z; t3 = tv.w;
        } else {
            const int eb = base + q * 4;
            t0 = (eb + 0 < n_edges) ? idx_i[eb + 0] : 0;
            t1 = (eb + 1 < n_edges) ? idx_i[eb + 1] : 0;
            t2 = (eb + 2 < n_edges) ? idx_i[eb + 2] : 0;
            t3 = (eb + 3 < n_edges) ? idx_i[eb + 3] : 0;
        }

        // ---- EARLY slot allocation (latency hides under MFMA work below) ----
        int pos_own = 0;
        if (USE_SLOTS) {
            int tsel = t0;
            tsel = (c == 1) ? t1 : tsel;
            tsel = (c == 2) ? t2 : tsel;
            tsel = (c == 3) ? t3 : tsel;
            if (c < 4 && (base + q * 4 + c) < n_edges)
                pos_own = atomicAdd(cnt + tsel, 1);
        }

        // ---- issue current group's data loads ----
        const float* xp = x + (size_t)jsrc * 16;
        float4 x0 = *reinterpret_cast<const float4*>(xp);
        float4 x1 = *reinterpret_cast<const float4*>(xp + 4);
        float4 x2 = *reinterpret_cast<const float4*>(xp + 8);
        float4 x3 = *reinterpret_cast<const float4*>(xp + 12);
        const float* ep = efeat + (size_t)el * 8;
        float4 e0 = *reinterpret_cast<const float4*>(ep);
        float4 e1 = *reinterpret_cast<const float4*>(ep + 4);

        // ---- prefetch next group's source index ----
        const int gn = g + nw;
        int  eidn = gn * 16 + c;
        bool van  = (eidn < n_edges);
        int  eln  = van ? eidn : (n_edges - 1);
        int  jn   = (gn < n_groups) ? idx_j[eln] : 0;

        // ---- h via MFMA: lane owns hd {4q..4q+3, 4q+16..4q+19} ----
        union { bf16x8_t bf; unsigned int u[4]; } bB;
        {
            unsigned int ef0 = cvt_pk_bf16(e0.x, e0.y);
            unsigned int ef1 = cvt_pk_bf16(e0.z, e0.w);
            unsigned int ef2 = cvt_pk_bf16(e1.x, e1.y);
            unsigned int ef3 = cvt_pk_bf16(e1.z, e1.w);
            bB.u[0] = isq0 ? ef0 : c1;
            bB.u[1] = isq0 ? ef1 : 0u;
            bB.u[2] = isq0 ? ef2 : 0u;
            bB.u[3] = isq0 ? ef3 : 0u;
        }
        f32x4_t z4 = {0.f, 0.f, 0.f, 0.f};
        f32x4_t h0 = __builtin_amdgcn_mfma_f32_16x16x32_bf16(aW1_0, bB.bf, z4, 0, 0, 0);
        f32x4_t h1 = __builtin_amdgcn_mfma_f32_16x16x32_bf16(aW1_1, bB.bf, z4, 0, 0, 0);

        float hown[8];
#pragma unroll
        for (int r = 0; r < 4; ++r) {
            hown[r]     = fmaxf(h0[r], 0.f);
            hown[4 + r] = fmaxf(h1[r], 0.f);
        }

        // ---- x fragment (zero rows for invalid edges) ----
        float xf[16];
        xf[0]=x0.x; xf[1]=x0.y; xf[2]=x0.z; xf[3]=x0.w;
        xf[4]=x1.x; xf[5]=x1.y; xf[6]=x1.z; xf[7]=x1.w;
        xf[8]=x2.x; xf[9]=x2.y; xf[10]=x2.z; xf[11]=x2.w;
        xf[12]=x3.x; xf[13]=x3.y; xf[14]=x3.z; xf[15]=x3.w;
        if (!va) {
#pragma unroll
            for (int t = 0; t < 16; ++t) xf[t] = 0.f;
        }

        // ---- b2-fold A fragment ----
        union { bf16x8_t bf; unsigned int u[4]; } xb;
        {
            float xs0 = qodd ? xf[8]  : xf[0];
            float xs1 = qodd ? xf[9]  : xf[1];
            float xs2 = qodd ? xf[10] : xf[2];
            float xs3 = qodd ? xf[11] : xf[3];
            float xs4 = qodd ? xf[12] : xf[4];
            float xs5 = qodd ? xf[13] : xf[5];
            float xs6 = qodd ? xf[14] : xf[6];
            float xs7 = qodd ? xf[15] : xf[7];
            xb.u[0] = cvt_pk_bf16(xs0, xs1);
            xb.u[1] = cvt_pk_bf16(xs2, xs3);
            xb.u[2] = cvt_pk_bf16(xs4, xs5);
            xb.u[3] = cvt_pk_bf16(xs6, xs7);
        }

        // ---- K loop: A[c][q*8+j] = bf16(hown[j] * x[f=s]), two acc chains ----
        f32x4_t acc0 = {0.f, 0.f, 0.f, 0.f};
        f32x4_t acc1 = {0.f, 0.f, 0.f, 0.f};
        union { bf16x8_t bf; unsigned int u[4]; } afr;
#pragma unroll
        for (int s = 0; s < 16; s += 2) {
            float xs = xf[s];
            afr.u[0] = cvt_pk_bf16(hown[0] * xs, hown[1] * xs);
            afr.u[1] = cvt_pk_bf16(hown[2] * xs, hown[3] * xs);
            afr.u[2] = cvt_pk_bf16(hown[4] * xs, hown[5] * xs);
            afr.u[3] = cvt_pk_bf16(hown[6] * xs, hown[7] * xs);
            acc0 = __builtin_amdgcn_mfma_f32_16x16x32_bf16(afr.bf, bW2[s], acc0, 0, 0, 0);
            xs = xf[s + 1];
            afr.u[0] = cvt_pk_bf16(hown[0] * xs, hown[1] * xs);
            afr.u[1] = cvt_pk_bf16(hown[2] * xs, hown[3] * xs);
            afr.u[2] = cvt_pk_bf16(hown[4] * xs, hown[5] * xs);
            afr.u[3] = cvt_pk_bf16(hown[6] * xs, hown[7] * xs);
            acc1 = __builtin_amdgcn_mfma_f32_16x16x32_bf16(afr.bf, bW2[s + 1], acc1, 0, 0, 0);
        }
        acc0 = __builtin_amdgcn_mfma_f32_16x16x32_bf16(xb.bf, bW2[16], acc0, 0, 0, 0);

        const float rr0 = acc0[0] + acc1[0];
        const float rr1 = acc0[1] + acc1[1];
        const float rr2 = acc0[2] + acc1[2];
        const float rr3 = acc0[3] + acc1[3];
        const int eb = base + q * 4;

        if (USE_SLOTS) {
            // broadcast slot positions from lanes 0..3 of this 16-lane group
            const int gb = lane & 48;
            const int p0 = __shfl(pos_own, gb + 0);
            const int p1 = __shfl(pos_own, gb + 1);
            const int p2 = __shfl(pos_own, gb + 2);
            const int p3 = __shfl(pos_own, gb + 3);
            if (eb + 0 < n_edges) {
                if (p0 < SLOTS) msgslot[((size_t)t0 * SLOTS + p0) * 16 + c] = rr0;
                else atomicAdd(out + (size_t)t0 * 16 + c, rr0);
            }
            if (eb + 1 < n_edges) {
                if (p1 < SLOTS) msgslot[((size_t)t1 * SLOTS + p1) * 16 + c] = rr1;
                else atomicAdd(out + (size_t)t1 * 16 + c, rr1);
            }
            if (eb + 2 < n_edges) {
                if (p2 < SLOTS) msgslot[((size_t)t2 * SLOTS + p2) * 16 + c] = rr2;
                else atomicAdd(out + (size_t)t2 * 16 + c, rr2);
            }
            if (eb + 3 < n_edges) {
                if (p3 < SLOTS) msgslot[((size_t)t3 * SLOTS + p3) * 16 + c] = rr3;
                else atomicAdd(out + (size_t)t3 * 16 + c, rr3);
            }
        } else {
            if (eb + 0 < n_edges) atomicAdd(out + (size_t)t0 * 16 + c, rr0);
            if (eb + 1 < n_edges) atomicAdd(out + (size_t)t1 * 16 + c, rr1);
            if (eb + 2 < n_edges) atomicAdd(out + (size_t)t2 * 16 + c, rr2);
            if (eb + 3 < n_edges) atomicAdd(out + (size_t)t3 * 16 + c, rr3);
        }

        jsrc = jn; el = eln; va = van;
    }
}

// ============ kernel 3: per-node slot reduction (16 lanes per node, no atomics) ============
__global__ __launch_bounds__(256) void gather_kernel(
    const float* __restrict__ msgslot,
    const int*   __restrict__ cnt,
    float* __restrict__ out,
    int n_nodes)
{
    int gi = blockIdx.x * 256 + threadIdx.x;
    int n = gi >> 4;
    int c = gi & 15;
    if (n >= n_nodes) return;

    int m = cnt[n];
    m = (m < SLOTS) ? m : SLOTS;

    const float* p = msgslot + (size_t)n * SLOTS * 16 + c;
    float s0 = 0.f, s1 = 0.f;
    int k = 0;
    for (; k + 1 < m; k += 2) {
        s0 += p[(size_t)k * 16];
        s1 += p[(size_t)(k + 1) * 16];
    }
    if (k < m) s0 += p[(size_t)k * 16];
    out[(size_t)n * 16 + c] += s0 + s1;
}

extern "C" void kernel_launch(void* const* d_in, const int* in_sizes, int n_in,
                              void* d_out, int out_size, void* d_ws, size_t ws_size,
                              hipStream_t stream) {
    const float* x     = (const float*)d_in[0];
    const float* e     = (const float*)d_in[1];
    const int*   idx_i = (const int*)d_in[2];
    const int*   idx_j = (const int*)d_in[3];
    const float* W1    = (const float*)d_in[4];
    const float* b1    = (const float*)d_in[5];
    const float* W2    = (const float*)d_in[6];
    const float* b2    = (const float*)d_in[7];
    const float* rootk = (const float*)d_in[8];
    const float* bias  = (const float*)d_in[9];

    int n_nodes  = in_sizes[0] / 16;
    int n_edges  = in_sizes[2];
    int n_groups = (n_edges + 15) / 16;

    float* out = (float*)d_out;
    unsigned short* tab = (unsigned short*)d_ws;                  // 19.5 KB
    int*   cnt     = (int*)((char*)d_ws + 65536);                 // n_nodes ints
    float* msgslot = (float*)((char*)d_ws + 524288);              // [N][SLOTS][16] f32

    size_t need = 524288 + (size_t)n_nodes * SLOTS * 16 * sizeof(float);
    const int use_slots = (ws_size >= need) ? 1 : 0;

    int root_blocks = (n_nodes + 255) / 256;
    prep_kernel<<<root_blocks + 1, 256, 0, stream>>>(x, W1, b1, W2, b2, rootk, bias,
                                                     out, tab, use_slots ? cnt : nullptr,
                                                     n_nodes, root_blocks);

    if (use_slots) {
        edge_mfma_kernel<1><<<2048, 256, 0, stream>>>(x, e, idx_i, idx_j, tab, out,
                                                      msgslot, cnt, n_edges, n_groups);
        int gblocks = (n_nodes * 16 + 255) / 256;
        gather_kernel<<<gblocks, 256, 0, stream>>>(msgslot, cnt, out, n_nodes);
    } else {
        edge_mfma_kernel<0><<<2048, 256, 0, stream>>>(x, e, idx_i, idx_j, tab, out,
                                                      msgslot, cnt, n_edges, n_groups);
    }
}

// Round 8
// 44.227 us; speedup vs baseline: 1.3021x; 1.3021x over previous
//
#include <hip/hip_runtime.h>

typedef __attribute__((ext_vector_type(8))) short bf16x8_t;   // 8 bf16 (4 VGPRs)
typedef __attribute__((ext_vector_type(4))) float f32x4_t;    // MFMA accumulator

__device__ __forceinline__ unsigned short f2bf(float f) {
    union { float f; unsigned int i; } v; v.f = f;
    unsigned int u = v.i;
    return (unsigned short)((u + 0x7FFFu + ((u >> 16) & 1u)) >> 16);   // RNE
}

__device__ __forceinline__ unsigned int cvt_pk_bf16(float lo, float hi) {
    unsigned int r;
    asm("v_cvt_pk_bf16_f32 %0, %1, %2" : "=v"(r) : "v"(lo), "v"(hi));
    return r;
}

#define LD4(p) (*reinterpret_cast<const float4*>(p))

// d_ws layout (u16): [0..1024) W1p h-MFMA A-frags; [1024..9728) W2p B-frags.

// ============ kernel 1: fused {root-init | fragment-table prep} ============
__global__ __launch_bounds__(256) void prep_kernel(
    const float* __restrict__ x,
    const float* __restrict__ W1,      // [8,32]
    const float* __restrict__ b1,      // [32]
    const float* __restrict__ W2,      // [32,256]
    const float* __restrict__ b2,      // [256]
    const float* __restrict__ rootk,   // [16,16]
    const float* __restrict__ bias,    // [16]
    float* __restrict__ out,           // [N,16]
    unsigned short* __restrict__ tab,
    int n_nodes, int root_blocks)
{
    const int tid = threadIdx.x;
    const int bid = blockIdx.x;

    if (bid < root_blocks) {
        __shared__ float sR[256];
        __shared__ float sB[16];
        if (tid < 256) sR[tid] = rootk[tid];
        if (tid < 16)  sB[tid] = bias[tid];
        __syncthreads();

        int nid = bid * 256 + tid;
        if (nid >= n_nodes) return;

        const float* xp = x + (size_t)nid * 16;
        float xf[16];
#pragma unroll
        for (int f = 0; f < 16; f += 4) {
            float4 v = LD4(xp + f);
            xf[f] = v.x; xf[f + 1] = v.y; xf[f + 2] = v.z; xf[f + 3] = v.w;
        }
        float o[16];
#pragma unroll
        for (int cc = 0; cc < 16; ++cc) o[cc] = sB[cc];
#pragma unroll
        for (int f = 0; f < 16; ++f) {
            float p = xf[f];
#pragma unroll
            for (int cc = 0; cc < 16; ++cc)
                o[cc] = fmaf(p, sR[f * 16 + cc], o[cc]);
        }
        float* dst = out + (size_t)nid * 16;
#pragma unroll
        for (int cc = 0; cc < 16; cc += 4)
            *reinterpret_cast<float4*>(dst + cc) = make_float4(o[cc], o[cc+1], o[cc+2], o[cc+3]);
    } else {
        // ---- fragment tables: 19 groups of 64 lanes ----
        for (int it = tid; it < 64 * 19; it += 256) {
            int grp  = it >> 6;         // 0,1 -> W1p halves; 2..18 -> W2p steps
            int lane = it & 63;
            int q = lane >> 4, cc = lane & 15;
            union { unsigned short h[8]; uint4 u; } pk;
            if (grp < 2) {
                int hh = grp;
#pragma unroll
                for (int j = 0; j < 8; ++j) {
                    float v = 0.f;
                    if (q == 0)              v = W1[j * 32 + cc + 16 * hh];
                    else if (q == 1 && j==0) v = b1[cc + 16 * hh];
                    pk.h[j] = f2bf(v);
                }
                *reinterpret_cast<uint4*>(tab + ((size_t)hh * 64 + lane) * 8) = pk.u;
            } else {
                int s = grp - 2;        // K-step
#pragma unroll
                for (int j = 0; j < 8; ++j) {
                    float v;
                    if (s < 16) {
                        int hd = (j < 4) ? (4 * q + j) : (4 * q + 12 + j);  // perm
                        v = W2[hd * 256 + s * 16 + cc];
                    } else {
                        v = (q < 2) ? b2[(q * 8 + j) * 16 + cc] : 0.f;       // b2 fold
                    }
                    pk.h[j] = f2bf(v);
                }
                *reinterpret_cast<uint4*>(tab + 1024 + ((size_t)s * 64 + lane) * 8) = pk.u;
            }
        }
    }
}

// ============ kernel 2: MFMA edge kernel — 4 contiguous groups/wave, straight-line pipeline ============
template<int EXACT>
__global__ __launch_bounds__(256) void edge_mfma_kernel(
    const float* __restrict__ x,       // [N,16]
    const float* __restrict__ efeat,   // [E,8]
    const int*   __restrict__ idx_i,
    const int*   __restrict__ idx_j,
    const unsigned short* __restrict__ tab,
    float* __restrict__ out,           // [N,16], pre-initialized with root term
    int n_edges, int n_groups)
{
    const int lane = threadIdx.x & 63;
    const int q = lane >> 4;
    const int c = lane & 15;

    // ---- per-wave fragment preload ----
    const bf16x8_t* w1f = reinterpret_cast<const bf16x8_t*>(tab) + lane;
    const bf16x8_t aW1_0 = w1f[0];
    const bf16x8_t aW1_1 = w1f[64];
    const bf16x8_t* w2f = reinterpret_cast<const bf16x8_t*>(tab + 1024) + lane;
    bf16x8_t bW2[17];
#pragma unroll
    for (int s = 0; s < 17; ++s) bW2[s] = w2f[s * 64];

    const unsigned int c1 = (q == 1) ? 0x00003F80u : 0u;   // bf16(1.0) one-hot for b1 row
    const bool isq0 = (q == 0);
    const bool qodd = (q & 1);
    float* const outc = out + c;

    const int wid = blockIdx.x * 4 + (threadIdx.x >> 6);
    const int g0  = wid * 4;
    if (g0 >= n_groups) return;
    const int rem = n_groups - g0;   // >= 1

    auto ldj = [&](int gg) -> int {
        int eid = gg * 16 + c;
        if (!EXACT) { if (eid >= n_edges) eid = n_edges - 1; }
        return idx_j[eid];
    };
    auto eoff = [&](int gg) -> size_t {
        int eid = gg * 16 + c;
        if (!EXACT) { if (eid >= n_edges) eid = n_edges - 1; }
        return (size_t)eid * 8;
    };

    auto compute = [&](float4 X0, float4 X1, float4 X2, float4 X3,
                       float4 E0, float4 E1, int gg) {
        // idx_i: issued now, consumed only at the very end (self-hiding)
        int t0, t1, t2, t3;
        if (EXACT || (gg * 16 + 16 <= n_edges)) {
            int4 tv = *reinterpret_cast<const int4*>(idx_i + gg * 16 + q * 4);
            t0 = tv.x; t1 = tv.y; t2 = tv.z; t3 = tv.w;
        } else {
            const int eb = gg * 16 + q * 4;
            t0 = (eb + 0 < n_edges) ? idx_i[eb + 0] : 0;
            t1 = (eb + 1 < n_edges) ? idx_i[eb + 1] : 0;
            t2 = (eb + 2 < n_edges) ? idx_i[eb + 2] : 0;
            t3 = (eb + 3 < n_edges) ? idx_i[eb + 3] : 0;
        }

        // ---- h via MFMA: lane owns hd {4q..4q+3, 4q+16..4q+19} ----
        union { bf16x8_t bf; unsigned int u[4]; } bB;
        {
            unsigned int ef0 = cvt_pk_bf16(E0.x, E0.y);
            unsigned int ef1 = cvt_pk_bf16(E0.z, E0.w);
            unsigned int ef2 = cvt_pk_bf16(E1.x, E1.y);
            unsigned int ef3 = cvt_pk_bf16(E1.z, E1.w);
            bB.u[0] = isq0 ? ef0 : c1;
            bB.u[1] = isq0 ? ef1 : 0u;
            bB.u[2] = isq0 ? ef2 : 0u;
            bB.u[3] = isq0 ? ef3 : 0u;
        }
        f32x4_t z4 = {0.f, 0.f, 0.f, 0.f};
        f32x4_t h0 = __builtin_amdgcn_mfma_f32_16x16x32_bf16(aW1_0, bB.bf, z4, 0, 0, 0);
        f32x4_t h1 = __builtin_amdgcn_mfma_f32_16x16x32_bf16(aW1_1, bB.bf, z4, 0, 0, 0);

        float hown[8];
#pragma unroll
        for (int r = 0; r < 4; ++r) {
            hown[r]     = fmaxf(h0[r], 0.f);
            hown[4 + r] = fmaxf(h1[r], 0.f);
        }

        float xf[16];
        xf[0]=X0.x; xf[1]=X0.y; xf[2]=X0.z; xf[3]=X0.w;
        xf[4]=X1.x; xf[5]=X1.y; xf[6]=X1.z; xf[7]=X1.w;
        xf[8]=X2.x; xf[9]=X2.y; xf[10]=X2.z; xf[11]=X2.w;
        xf[12]=X3.x; xf[13]=X3.y; xf[14]=X3.z; xf[15]=X3.w;
        // (garbage rows for invalid edges are harmless: D rows are per-edge,
        //  and invalid rows' atomics are guarded below)

        // ---- b2-fold A fragment ----
        union { bf16x8_t bf; unsigned int u[4]; } xb;
        xb.u[0] = cvt_pk_bf16(qodd ? xf[8]  : xf[0], qodd ? xf[9]  : xf[1]);
        xb.u[1] = cvt_pk_bf16(qodd ? xf[10] : xf[2], qodd ? xf[11] : xf[3]);
        xb.u[2] = cvt_pk_bf16(qodd ? xf[12] : xf[4], qodd ? xf[13] : xf[5]);
        xb.u[3] = cvt_pk_bf16(qodd ? xf[14] : xf[6], qodd ? xf[15] : xf[7]);

        // ---- K loop: A[c][q*8+j] = bf16(hown[j] * x[f=s]), two acc chains ----
        f32x4_t acc0 = {0.f, 0.f, 0.f, 0.f};
        f32x4_t acc1 = {0.f, 0.f, 0.f, 0.f};
        union { bf16x8_t bf; unsigned int u[4]; } afr;
#pragma unroll
        for (int s = 0; s < 16; s += 2) {
            float xs = xf[s];
            afr.u[0] = cvt_pk_bf16(hown[0] * xs, hown[1] * xs);
            afr.u[1] = cvt_pk_bf16(hown[2] * xs, hown[3] * xs);
            afr.u[2] = cvt_pk_bf16(hown[4] * xs, hown[5] * xs);
            afr.u[3] = cvt_pk_bf16(hown[6] * xs, hown[7] * xs);
            acc0 = __builtin_amdgcn_mfma_f32_16x16x32_bf16(afr.bf, bW2[s], acc0, 0, 0, 0);
            xs = xf[s + 1];
            afr.u[0] = cvt_pk_bf16(hown[0] * xs, hown[1] * xs);
            afr.u[1] = cvt_pk_bf16(hown[2] * xs, hown[3] * xs);
            afr.u[2] = cvt_pk_bf16(hown[4] * xs, hown[5] * xs);
            afr.u[3] = cvt_pk_bf16(hown[6] * xs, hown[7] * xs);
            acc1 = __builtin_amdgcn_mfma_f32_16x16x32_bf16(afr.bf, bW2[s + 1], acc1, 0, 0, 0);
        }
        acc0 = __builtin_amdgcn_mfma_f32_16x16x32_bf16(xb.bf, bW2[16], acc0, 0, 0, 0);

        const float rr0 = acc0[0] + acc1[0];
        const float rr1 = acc0[1] + acc1[1];
        const float rr2 = acc0[2] + acc1[2];
        const float rr3 = acc0[3] + acc1[3];
        if (EXACT) {
            atomicAdd(outc + (size_t)t0 * 16, rr0);
            atomicAdd(outc + (size_t)t1 * 16, rr1);
            atomicAdd(outc + (size_t)t2 * 16, rr2);
            atomicAdd(outc + (size_t)t3 * 16, rr3);
        } else {
            const int eb = gg * 16 + q * 4;
            if (eb + 0 < n_edges) atomicAdd(outc + (size_t)t0 * 16, rr0);
            if (eb + 1 < n_edges) atomicAdd(outc + (size_t)t1 * 16, rr1);
            if (eb + 2 < n_edges) atomicAdd(outc + (size_t)t2 * 16, rr2);
            if (eb + 3 < n_edges) atomicAdd(outc + (size_t)t3 * 16, rr3);
        }
    };

#define STAGE(B0,B1,B2,B3,BE0,BE1, jv, gg)                         \
    {                                                              \
        const float* xp = x + (size_t)(jv) * 16;                   \
        B0 = LD4(xp); B1 = LD4(xp + 4);                            \
        B2 = LD4(xp + 8); B3 = LD4(xp + 12);                       \
        const float* ep = efeat + eoff(gg);                        \
        BE0 = LD4(ep); BE1 = LD4(ep + 4);                          \
    }

    // ---- all 4 source indices in flight first ----
    const int jA = ldj(g0);
    const int jB = (rem > 1) ? ldj(g0 + 1) : 0;
    const int jC = (rem > 2) ? ldj(g0 + 2) : 0;
    const int jD = (rem > 3) ? ldj(g0 + 3) : 0;

    float4 a0, a1, a2, a3, ae0, ae1;
    float4 b0, b1, b2, b3, be0, be1;

    STAGE(a0,a1,a2,a3,ae0,ae1, jA, g0);
    if (rem > 1) STAGE(b0,b1,b2,b3,be0,be1, jB, g0 + 1);
    compute(a0,a1,a2,a3,ae0,ae1, g0);
    if (rem > 1) {
        if (rem > 2) STAGE(a0,a1,a2,a3,ae0,ae1, jC, g0 + 2);
        compute(b0,b1,b2,b3,be0,be1, g0 + 1);
        if (rem > 2) {
            if (rem > 3) STAGE(b0,b1,b2,b3,be0,be1, jD, g0 + 3);
            compute(a0,a1,a2,a3,ae0,ae1, g0 + 2);
            if (rem > 3) compute(b0,b1,b2,b3,be0,be1, g0 + 3);
        }
    }
#undef STAGE
}

extern "C" void kernel_launch(void* const* d_in, const int* in_sizes, int n_in,
                              void* d_out, int out_size, void* d_ws, size_t ws_size,
                              hipStream_t stream) {
    const float* x     = (const float*)d_in[0];
    const float* e     = (const float*)d_in[1];
    const int*   idx_i = (const int*)d_in[2];
    const int*   idx_j = (const int*)d_in[3];
    const float* W1    = (const float*)d_in[4];
    const float* b1    = (const float*)d_in[5];
    const float* W2    = (const float*)d_in[6];
    const float* b2    = (const float*)d_in[7];
    const float* rootk = (const float*)d_in[8];
    const float* bias  = (const float*)d_in[9];

    int n_nodes  = in_sizes[0] / 16;
    int n_edges  = in_sizes[2];
    int n_groups = (n_edges + 15) / 16;

    float* out = (float*)d_out;
    unsigned short* tab = (unsigned short*)d_ws;   // 19.5 KB used

    int root_blocks = (n_nodes + 255) / 256;
    prep_kernel<<<root_blocks + 1, 256, 0, stream>>>(x, W1, b1, W2, b2, rootk, bias,
                                                     out, tab, n_nodes, root_blocks);

    // 4 waves/block, 4 contiguous groups per wave
    int blocks = (n_groups + 15) / 16;
    if ((n_edges & 15) == 0)
        edge_mfma_kernel<1><<<blocks, 256, 0, stream>>>(x, e, idx_i, idx_j, tab, out,
                                                        n_edges, n_groups);
    else
        edge_mfma_kernel<0><<<blocks, 256, 0, stream>>>(x, e, idx_i, idx_j, tab, out,
                                                        n_edges, n_groups);
}